// Round 1
// baseline (455.788 us; speedup 1.0000x reference)
//
#include <hip/hip_runtime.h>
#include <hip/hip_bf16.h>
#include <stdint.h>

// TubeletEmbedding: video [64,16,1,84,84] f32 -> tubelets [73728,98] -> GEMM
// with W [1024,98] (B^T layout) -> out [64,1152,1024] f32 + bias + pos_embed.
// Output-write-bound (302 MB fp32). bf16 MFMA for the GEMM (tolerance 0.135).

typedef __bf16 bf16_t;
typedef bf16_t bf16x8 __attribute__((ext_vector_type(8)));
typedef float f32x4 __attribute__((ext_vector_type(4)));

#define B_      64
#define N_TOK   1152
#define M_TOT   (B_ * N_TOK)   // 73728
#define E_      1024
#define KP      128            // padded K (real K = 98)
#define K_REAL  98
#define BM      128
#define BN      128
#define MT_N    (M_TOT / BM)   // 576 M-tiles
#define NT_N    (E_ / BN)      // 8  N-tiles

// ---- pass 1a: W f32 [1024][98] -> bf16 [1024][128] zero-padded ----
__global__ void wconv_kernel(const float* __restrict__ W, bf16_t* __restrict__ Wb) {
    int idx = blockIdx.x * 256 + threadIdx.x;   // covers 1024*128
    int k = idx & (KP - 1);
    int e = idx >> 7;
    float v = (k < K_REAL) ? W[e * K_REAL + k] : 0.f;
    Wb[idx] = (bf16_t)v;
}

// ---- pass 1b: im2col gather video -> A_ws bf16 [73728][128] zero-padded ----
// tubelets[m, k]: m = b*1152 + d*144 + s, k = ts*49 + py*7 + px
//   -> video[b, 2d+ts, (s/12)*7+py, (s%12)*7+px]
__global__ void im2col_kernel(const float* __restrict__ video, bf16_t* __restrict__ A) {
    int idx = blockIdx.x * 256 + threadIdx.x;   // covers 73728*128
    int k = idx & (KP - 1);
    int m = idx >> 7;
    float v = 0.f;
    if (k < K_REAL) {
        int b  = m / N_TOK;
        int n  = m - b * N_TOK;
        int d  = n / 144, s = n - d * 144;
        int ts = (k >= 49) ? 1 : 0;
        int f  = k - ts * 49;
        int i  = s / 12, j = s - i * 12;
        int fy = f / 7,  fx = f - fy * 7;
        int t  = d * 2 + ts;
        int y  = i * 7 + fy;
        int x  = j * 7 + fx;
        v = video[(b * 16 + t) * 7056 + y * 84 + x];
    }
    A[idx] = (bf16_t)v;
}

// ---- pass 2: GEMM 128x128 tile, K=128 one-shot LDS, bf16 MFMA ----
__global__ __launch_bounds__(256) void gemm_kernel(
    const bf16_t* __restrict__ A, const bf16_t* __restrict__ Wb,
    const float* __restrict__ bias, const float* __restrict__ pos,
    float* __restrict__ out) {
    __shared__ __align__(16) bf16_t As[BM * KP];   // 32 KB
    __shared__ __align__(16) bf16_t Bs[BN * KP];   // 32 KB

    const int tid  = threadIdx.x;
    const int wv   = tid >> 6;
    const int lane = tid & 63;

    // mt = bid % 576: all 8 N-tiles of one M-tile land on the same XCD
    // (dispatch round-robins bid%8 across XCDs) -> A-tile L2 reuse.
    const int bid = blockIdx.x;
    const int mt  = bid % MT_N;
    const int nt  = bid / MT_N;
    const long m0 = (long)mt * BM;
    const int  n0 = nt * BN;

    // Stage A-tile and B-tile: each is a fully contiguous 32 KB global region.
    {
        const char* gA = (const char*)(A + m0 * KP);
        const char* gB = (const char*)(Wb + (long)n0 * KP);
        char* lA = (char*)As;
        char* lB = (char*)Bs;
#pragma unroll
        for (int i = 0; i < 8; ++i) {
            int off = (wv * 8 + i) * 1024;
            __builtin_amdgcn_global_load_lds(
                (const __attribute__((address_space(1))) void*)(gA + off + lane * 16),
                (__attribute__((address_space(3))) void*)(lA + off), 16, 0, 0);
        }
#pragma unroll
        for (int i = 0; i < 8; ++i) {
            int off = (wv * 8 + i) * 1024;
            __builtin_amdgcn_global_load_lds(
                (const __attribute__((address_space(1))) void*)(gB + off + lane * 16),
                (__attribute__((address_space(3))) void*)(lB + off), 16, 0, 0);
        }
    }
    __syncthreads();

    const int wr = wv >> 1, wc = wv & 1;   // 2x2 waves, each 64x64 output
    const int lr = lane & 15;              // A-row / B-col within fragment
    const int lk = (lane >> 4) * 8;        // k-offset within fragment

    f32x4 acc[4][4];
#pragma unroll
    for (int mi = 0; mi < 4; ++mi)
#pragma unroll
        for (int ni = 0; ni < 4; ++ni)
            acc[mi][ni] = (f32x4){0.f, 0.f, 0.f, 0.f};

#pragma unroll
    for (int kk = 0; kk < 4; ++kk) {
        bf16x8 a[4], b[4];
#pragma unroll
        for (int mi = 0; mi < 4; ++mi)
            a[mi] = *(const bf16x8*)&As[(wr * 64 + mi * 16 + lr) * KP + kk * 32 + lk];
#pragma unroll
        for (int ni = 0; ni < 4; ++ni)
            b[ni] = *(const bf16x8*)&Bs[(wc * 64 + ni * 16 + lr) * KP + kk * 32 + lk];
#pragma unroll
        for (int mi = 0; mi < 4; ++mi)
#pragma unroll
            for (int ni = 0; ni < 4; ++ni)
                acc[mi][ni] = __builtin_amdgcn_mfma_f32_16x16x32_bf16(
                    a[mi], b[ni], acc[mi][ni], 0, 0, 0);
    }

    // Epilogue: out[m][e] = acc + bias[e] + pos[m % 1152][e]
    // C/D layout: col = lane&15, row = (lane>>4)*4 + reg  (m89-verified)
    const int ntok_blk = (mt % 9) * BM;    // 1152 = 9 tiles of 128: no division
    const int row4 = (lane >> 4) * 4;
#pragma unroll
    for (int ni = 0; ni < 4; ++ni) {
        const int e  = n0 + wc * 64 + ni * 16 + lr;
        const float be = bias[e];
#pragma unroll
        for (int mi = 0; mi < 4; ++mi) {
            const int mloc = wr * 64 + mi * 16 + row4;
            const long mg  = m0 + mloc;
            const int ntok = ntok_blk + mloc;
#pragma unroll
            for (int r = 0; r < 4; ++r) {
                out[(mg + r) * (long)E_ + e] =
                    acc[mi][ni][r] + be + pos[(ntok + r) * E_ + e];
            }
        }
    }
}

extern "C" void kernel_launch(void* const* d_in, const int* in_sizes, int n_in,
                              void* d_out, int out_size, void* d_ws, size_t ws_size,
                              hipStream_t stream) {
    const float* video = (const float*)d_in[0];  // 64*16*1*84*84
    const float* W     = (const float*)d_in[1];  // 1024*98
    const float* bias  = (const float*)d_in[2];  // 1024
    const float* pos   = (const float*)d_in[3];  // 1*1152*1024
    float* out = (float*)d_out;

    bf16_t* A_ws = (bf16_t*)d_ws;                                  // 73728*128*2 = 18.9 MB
    bf16_t* W_ws = (bf16_t*)((char*)d_ws + (size_t)M_TOT * KP * 2); // + 256 KB

    wconv_kernel<<<(E_ * KP) / 256, 256, 0, stream>>>(W, W_ws);
    im2col_kernel<<<(M_TOT * KP) / 256, 256, 0, stream>>>(video, A_ws);
    gemm_kernel<<<MT_N * NT_N, 256, 0, stream>>>(A_ws, W_ws, bias, pos, out);
}

// Round 2
// 443.913 us; speedup vs baseline: 1.0268x; 1.0268x over previous
//
#include <hip/hip_runtime.h>
#include <hip/hip_bf16.h>
#include <stdint.h>

// TubeletEmbedding: video [64,16,1,84,84] f32 -> tubelets [73728,98] -> GEMM
// with W [1024,98] (B^T layout) -> out [64,1152,1024] f32 + bias + pos_embed.
// Output-write-bound (302 MB fp32). bf16 MFMA (tolerance 0.135, measured 0.031).
//
// R1: A_ws/W_ws stored PRE-SWIZZLED (k ^= (row&7)<<3 on 8-bf16 granules) so the
// linear global_load_lds + swizzled ds_read kills the 16-way bank conflict of
// 256B-stride rows (rule #21: swizzle both sides or neither).

typedef __bf16 bf16_t;
typedef bf16_t bf16x8 __attribute__((ext_vector_type(8)));
typedef float f32x4 __attribute__((ext_vector_type(4)));

#define B_      64
#define N_TOK   1152
#define M_TOT   (B_ * N_TOK)   // 73728
#define E_      1024
#define KP      128            // padded K (real K = 98)
#define K_REAL  98
#define BM      128
#define BN      128
#define MT_N    (M_TOT / BM)   // 576 M-tiles
#define NT_N    (E_ / BN)      // 8  N-tiles

// ---- pass 1a: W f32 [1024][98] -> bf16 [1024][128], zero-pad, swizzled ----
__global__ void wconv_kernel(const float* __restrict__ W, bf16_t* __restrict__ Wb) {
    int idx = blockIdx.x * 256 + threadIdx.x;   // covers 1024*128
    int k = idx & (KP - 1);
    int e = idx >> 7;
    float v = (k < K_REAL) ? W[e * K_REAL + k] : 0.f;
    Wb[e * KP + (k ^ ((e & 7) << 3))] = (bf16_t)v;
}

// ---- pass 1b: im2col gather video -> A_ws bf16 [73728][128], swizzled ----
// One thread per 16B granule: 8 gathered f32 -> bf16x8 -> one coalesced store.
// tubelets[m, k]: m = b*1152 + d*144 + s, k = ts*49 + fy*7 + fx
//   -> video[b, 2d+ts, (s/12)*7+fy, (s%12)*7+fx]
__global__ void im2col_kernel(const float* __restrict__ video, bf16_t* __restrict__ A) {
    int idx = blockIdx.x * 256 + threadIdx.x;   // covers 73728*16
    int g = idx & 15;
    int m = idx >> 4;
    int b  = m / N_TOK;
    int n  = m - b * N_TOK;
    int d  = n / 144, s = n - d * 144;
    int i  = s / 12,  jj = s - i * 12;
    const float* base = video + (b * 16 + d * 2) * 7056 + (i * 7) * 84 + jj * 7;
    bf16_t vals[8];
#pragma unroll
    for (int j = 0; j < 8; ++j) {
        int k = g * 8 + j;
        float v = 0.f;
        if (k < K_REAL) {
            int ts = (k >= 49) ? 1 : 0;
            int f  = k - ts * 49;
            int fy = f / 7, fx = f - fy * 7;
            v = base[ts * 7056 + fy * 84 + fx];
        }
        vals[j] = (bf16_t)v;
    }
    int col = (g * 8) ^ ((m & 7) << 3);
    *(bf16x8*)&A[(long)m * KP + col] = *(const bf16x8*)vals;
}

// ---- pass 2: GEMM 128x128 tile, K=128 one-shot LDS, bf16 MFMA ----
__global__ __launch_bounds__(256) void gemm_kernel(
    const bf16_t* __restrict__ A, const bf16_t* __restrict__ Wb,
    const float* __restrict__ bias, const float* __restrict__ pos,
    float* __restrict__ out) {
    __shared__ __align__(16) bf16_t As[BM * KP];   // 32 KB
    __shared__ __align__(16) bf16_t Bs[BN * KP];   // 32 KB

    const int tid  = threadIdx.x;
    const int wv   = tid >> 6;
    const int lane = tid & 63;

    const int bid = blockIdx.x;
    const int mt  = bid % MT_N;
    const int nt  = bid / MT_N;
    const long m0 = (long)mt * BM;
    const int  n0 = nt * BN;

    // Stage A-tile and B-tile: each a fully contiguous 32 KB global region
    // (already swizzled in global memory; gload_lds copies linearly).
    {
        const char* gA = (const char*)(A + m0 * KP);
        const char* gB = (const char*)(Wb + (long)n0 * KP);
        char* lA = (char*)As;
        char* lB = (char*)Bs;
#pragma unroll
        for (int i = 0; i < 8; ++i) {
            int off = (wv * 8 + i) * 1024;
            __builtin_amdgcn_global_load_lds(
                (const __attribute__((address_space(1))) void*)(gA + off + lane * 16),
                (__attribute__((address_space(3))) void*)(lA + off), 16, 0, 0);
        }
#pragma unroll
        for (int i = 0; i < 8; ++i) {
            int off = (wv * 8 + i) * 1024;
            __builtin_amdgcn_global_load_lds(
                (const __attribute__((address_space(1))) void*)(gB + off + lane * 16),
                (__attribute__((address_space(3))) void*)(lB + off), 16, 0, 0);
        }
    }
    __syncthreads();

    const int wr = wv >> 1, wc = wv & 1;   // 2x2 waves, each 64x64 output
    const int lr = lane & 15;              // A-row / B-col within fragment
    const int lk = (lane >> 4) * 8;        // k-offset within fragment
    const int xsw = (lr & 7) << 3;         // row&7 == lr&7 for all fragments

    f32x4 acc[4][4];
#pragma unroll
    for (int mi = 0; mi < 4; ++mi)
#pragma unroll
        for (int ni = 0; ni < 4; ++ni)
            acc[mi][ni] = (f32x4){0.f, 0.f, 0.f, 0.f};

#pragma unroll
    for (int kk = 0; kk < 4; ++kk) {
        bf16x8 a[4], b[4];
        const int col = (kk * 32 + lk) ^ xsw;   // swizzled k-granule
#pragma unroll
        for (int mi = 0; mi < 4; ++mi)
            a[mi] = *(const bf16x8*)&As[(wr * 64 + mi * 16 + lr) * KP + col];
#pragma unroll
        for (int ni = 0; ni < 4; ++ni)
            b[ni] = *(const bf16x8*)&Bs[(wc * 64 + ni * 16 + lr) * KP + col];
#pragma unroll
        for (int mi = 0; mi < 4; ++mi)
#pragma unroll
            for (int ni = 0; ni < 4; ++ni)
                acc[mi][ni] = __builtin_amdgcn_mfma_f32_16x16x32_bf16(
                    a[mi], b[ni], acc[mi][ni], 0, 0, 0);
    }

    // Epilogue: out[m][e] = acc + bias[e] + pos[m % 1152][e]
    // C/D layout: col = lane&15, row = (lane>>4)*4 + reg  (m89-verified)
    const int ntok_blk = (mt % 9) * BM;    // 1152 = 9 tiles of 128
    const int row4 = (lane >> 4) * 4;
#pragma unroll
    for (int ni = 0; ni < 4; ++ni) {
        const int e  = n0 + wc * 64 + ni * 16 + lr;
        const float be = bias[e];
#pragma unroll
        for (int mi = 0; mi < 4; ++mi) {
            const int mloc = wr * 64 + mi * 16 + row4;
            const long mg  = m0 + mloc;
            const int ntok = ntok_blk + mloc;
#pragma unroll
            for (int r = 0; r < 4; ++r) {
                float vout = acc[mi][ni][r] + be + pos[(ntok + r) * E_ + e];
                __builtin_nontemporal_store(vout, &out[(mg + r) * (long)E_ + e]);
            }
        }
    }
}

extern "C" void kernel_launch(void* const* d_in, const int* in_sizes, int n_in,
                              void* d_out, int out_size, void* d_ws, size_t ws_size,
                              hipStream_t stream) {
    const float* video = (const float*)d_in[0];  // 64*16*1*84*84
    const float* W     = (const float*)d_in[1];  // 1024*98
    const float* bias  = (const float*)d_in[2];  // 1024
    const float* pos   = (const float*)d_in[3];  // 1*1152*1024
    float* out = (float*)d_out;

    bf16_t* A_ws = (bf16_t*)d_ws;                                   // 18.9 MB
    bf16_t* W_ws = (bf16_t*)((char*)d_ws + (size_t)M_TOT * KP * 2); // +256 KB

    wconv_kernel<<<(E_ * KP) / 256, 256, 0, stream>>>(W, W_ws);
    im2col_kernel<<<(M_TOT * 16) / 256, 256, 0, stream>>>(video, A_ws);
    gemm_kernel<<<MT_N * NT_N, 256, 0, stream>>>(A_ws, W_ws, bias, pos, out);
}